// Round 9
// baseline (201.984 us; speedup 1.0000x reference)
//
#include <hip/hip_runtime.h>
#include <hip/hip_fp16.h>
#include <math.h>

#define BN_EPS 1e-5f

__device__ __forceinline__ float max3f(float a, float b, float c) {
    return fmaxf(fmaxf(a, b), c);
}

// Two blocks per (b,c) plane (half = 32 gate rows / 96 out rows each), 128 threads
// = 2 waves. ~16 blocks/CU resident -> continuous churn destaggers phases across
// blocks (B-compute overlaps other blocks' A-reads / C-writes).
// Phase A: streaming separable blurpool(maxpool3x3(x)) with 4-deep prefetch ring
//          -> fp16 tile sxp_h[44][84] (gate rows B0-6..B0+37 @ +6, cols @ +8, zero halo)
// Phase B: four directional 33-tap convs (fp16 LDS reads, f32 accumulate)
// Phase C: out = x * gate[i/3][j/3]  (plain stores — NT store caused post-timing
//          divergence in round 8: stale dirty L2 lines vs bypassing writes)
__global__ __launch_bounds__(128, 8)
void mra_fused(const float* __restrict__ x,
               const float* __restrict__ wh1,
               const float* __restrict__ wv1,
               const float* __restrict__ wh2,
               const float* __restrict__ wv2,
               const float* __restrict__ bng,
               const float* __restrict__ bnb,
               const float* __restrict__ bnm,
               const float* __restrict__ bnv,
               float* __restrict__ out)
{
    __shared__ __align__(16) __half sxp_h[44][84];     // 7.2 KB
    __shared__ __align__(16) float  rowbuf[2][2][192]; // 3 KB per-wave dbuf

    const int bid   = blockIdx.x;       // 4096 = 2048 planes x 2 halves
    const int plane = bid >> 1;
    const int half  = bid & 1;
    const int c     = plane & 255;
    const int B0    = half << 5;        // gate-row base: 0 or 32
    const int tid   = threadIdx.x;
    const int lane  = tid & 63;
    const int wv    = tid >> 6;         // 0..1
    const float* __restrict__ xp = x   + (size_t)plane * 36864;
    float* __restrict__       op = out + (size_t)plane * 36864;

    // ---- zero LDS tile (row/col halo must be 0 for conv boundary) ----
    {
        int* z = (int*)&sxp_h[0][0];
        const int nInt = (44 * 84 * 2) / 4;   // 1848
        #pragma unroll
        for (int i = 0; i < 15; ++i) {
            const int idx = tid + (i << 7);
            if (idx < nInt) z[idx] = 0;
        }
    }
    __syncthreads();

    // ---- Phase A: streaming maxpool3x3(SAME) + blur4x4 stride-3 ----
    // wave wv computes x_tem rows T0..T0+21 (T0 = B0-6+22*wv); lane owns col q=lane.
    // 69 source rows streamed with a 4-deep float4 prefetch ring.
    {
        const int T0 = B0 - 6 + 22 * wv;
        float* rb0 = rowbuf[wv][0];
        float* rb1 = rowbuf[wv][1];
        const int i0 = (lane == 0) ? 1 : 3 * lane - 1;  // reflect: col -1 == col 1
        const int i1 = 3 * lane, i2 = 3 * lane + 1, i3 = 3 * lane + 2;
        const int r0 = 3 * T0 - 2;

        float4 ring[4];
        auto issue = [&](int k, float4* slot) {
            int r = r0 + k;
            r = r < 0 ? 0 : (r > 191 ? 191 : r);   // clamp == maxpool SAME
            float4 v = make_float4(0.f, 0.f, 0.f, 0.f);
            if (lane < 48) v = *(const float4*)(xp + r * 192 + 4 * lane);
            *slot = v;
        };
        issue(0, &ring[0]); issue(1, &ring[1]);
        issue(2, &ring[2]); issue(3, &ring[3]);

        float h[3][4];     // hmax history of last 3 source rows
        float hb[3];       // blur-row values for current output row
        float hbp = 0.f;   // previous blur-row (center 3t-1)

        #pragma unroll
        for (int k = 0; k < 69; ++k) {
            float4 v4 = ring[k & 3];               // vmcnt wait lands here
            if (k + 4 < 69) issue(k + 4, &ring[k & 3]);

            float nl = __shfl_up(v4.w, 1);
            float nr = __shfl_down(v4.x, 1);
            if (lane == 0)  nl = v4.x;
            if (lane == 47) nr = v4.w;
            float* rb = (k & 1) ? rb1 : rb0;
            if (lane < 48) {
                float4 hm;
                hm.x = max3f(nl,   v4.x, v4.y);
                hm.y = max3f(v4.x, v4.y, v4.z);
                hm.z = max3f(v4.y, v4.z, v4.w);
                hm.w = max3f(v4.z, v4.w, nr);
                *(float4*)(rb + 4 * lane) = hm;
            }
            __builtin_amdgcn_wave_barrier();   // required: cross-lane write->read
            float* hk = h[k % 3];
            hk[0] = rb[i0]; hk[1] = rb[i1]; hk[2] = rb[i2]; hk[3] = rb[i3];
            __builtin_amdgcn_wave_barrier();   // required: read -> next write (WAR)

            if (k >= 2) {
                const float* a = h[(k - 2) % 3];
                const float* b = h[(k - 1) % 3];
                const float* d = h[k % 3];
                const float e4 =
                      0.125f * max3f(a[0], b[0], d[0])
                    + 0.375f * max3f(a[1], b[1], d[1])
                    + 0.375f * max3f(a[2], b[2], d[2])
                    + 0.125f * max3f(a[3], b[3], d[3]);
                if (k == 2) {
                    hbp = e4;                       // center row 3*T0-1
                } else {
                    hb[k % 3] = e4;                 // k%3: 0->hb0, 1->hb1, 2->hb2
                    if (k % 3 == 2) {
                        const int t = T0 + (k - 5) / 3;   // x_tem row
                        float a_out;
                        if (t == 0)                 // top reflect: center -1 == 1
                            a_out = 0.375f * hb[0] + 0.5f * hb[1] + 0.125f * hb[2];
                        else
                            a_out = 0.125f * hbp + 0.375f * hb[0]
                                  + 0.375f * hb[1] + 0.125f * hb[2];
                        hbp = hb[2];
                        if (t >= 0 && t <= 63)
                            sxp_h[t - (B0 - 6)][lane + 8] = __float2half(a_out);
                    }
                }
            }
        }
    }
    __syncthreads();

    // ---- Phase B: four directional 33-tap depthwise convs ----
    // thread: gate row p_loc = tid>>2 (0..31), strip q0..q0+15, q0 = 16*(tid&3)
    const int p_loc = tid >> 2;
    const int q0    = (tid & 3) << 4;
    float acc[16];
    #pragma unroll
    for (int i = 0; i < 16; ++i) acc[i] = 0.0f;

    const float* __restrict__ wh1p = wh1 + c * 33;
    const float* __restrict__ wv1p = wv1 + c * 33;
    const float* __restrict__ wh2p = wh2 + c * 33;
    const float* __restrict__ wv2p = wv2 + c * 33;

    #pragma unroll
    for (int e = -6; e <= 6; ++e) {
        // rbx[j] = X(p+e, q0-8+j); LDS row p_loc+e+6 in [0,43], halo gives zeros
        float rbx[32];
        const __half* rowl = &sxp_h[p_loc + e + 6][q0];
        #pragma unroll
        for (int u = 0; u < 8; ++u) {
            const __half2* h2p = (const __half2*)(rowl + 4 * u);
            const float2 f0 = __half22float2(h2p[0]);
            const float2 f1 = __half22float2(h2p[1]);
            rbx[4 * u + 0] = f0.x; rbx[4 * u + 1] = f0.y;
            rbx[4 * u + 2] = f1.x; rbx[4 * u + 3] = f1.y;
        }
        if (e >= -5 && e <= 5) {
            #pragma unroll
            for (int dw = -1; dw <= 1; ++dw) {
                const float wt = wh1p[(e + 5) * 3 + dw + 1];
                #pragma unroll
                for (int i = 0; i < 16; ++i) acc[i] += wt * rbx[i + dw + 8];
            }
            #pragma unroll
            for (int dw = -1; dw <= 1; ++dw) {
                const float wt = wh2p[(e + 5) * 3 + dw + 1];
                #pragma unroll
                for (int i = 0; i < 16; ++i) acc[i] += wt * rbx[i + dw - e + 8];
            }
        }
        if (e >= -1 && e <= 1) {
            #pragma unroll
            for (int dw = -5; dw <= 5; ++dw) {
                const float wt = wv1p[(e + 1) * 11 + dw + 5];
                #pragma unroll
                for (int i = 0; i < 16; ++i) acc[i] += wt * rbx[i + dw + 8];
            }
        }
        #pragma unroll
        for (int dh = -1; dh <= 1; ++dh) {
            const int dw = dh - e;
            if (dw >= -5 && dw <= 5) {
                const float wt = wv2p[(dh + 1) * 11 + dw + 5];
                #pragma unroll
                for (int i = 0; i < 16; ++i) acc[i] += wt * rbx[i + dh - e + 8];
            }
        }
    }

    // ---- BN (inference) + sigmoid -> gate, stored back over LDS tile (fp16) ----
    const float inv = bng[c] * rsqrtf(bnv[c] + BN_EPS);
    const float mu  = bnm[c];
    const float bt  = bnb[c];
    __syncthreads();   // all conv reads of sxp_h done before overwrite
    #pragma unroll
    for (int i = 0; i < 8; ++i) {
        const float a0 = (acc[2 * i]     - mu) * inv + bt;
        const float a1 = (acc[2 * i + 1] - mu) * inv + bt;
        const float g0 = 1.0f / (1.0f + __expf(-a0));
        const float g1 = 1.0f / (1.0f + __expf(-a1));
        *(__half2*)(&sxp_h[p_loc + 6][q0 + 2 * i + 8]) = __floats2half2_rn(g0, g1);
    }
    __syncthreads();

    // ---- Phase C: out rows 96*half..96*half+95 = x * gate, float4 stores ----
    const float4* __restrict__ x4 = (const float4*)xp + half * (96 * 48);
    float4* __restrict__       o4 = (float4*)op       + half * (96 * 48);
    int rowj[3], gcj[3], rrj[3];
    #pragma unroll
    for (int j = 0; j < 3; ++j) {
        const int idx0 = tid + (j << 7);
        const int rw   = idx0 / 48;            // 192/4=48 float4 per row
        const int c4   = idx0 - rw * 48;
        rowj[j] = rw;
        const int jb = c4 << 2;
        gcj[j] = jb / 3;
        rrj[j] = jb - 3 * gcj[j];
    }
    #pragma unroll
    for (int m = 0; m < 12; ++m) {
        #pragma unroll
        for (int j = 0; j < 3; ++j) {
            const int row = rowj[j] + (m << 3);        // 0..95 within half
            const int idx = tid + ((m * 3 + j) << 7);
            const int gr  = row / 3 + 6;               // LDS gate row
            const float g0 = __half2float(sxp_h[gr][gcj[j] + 8]);
            const float g1 = __half2float(sxp_h[gr][gcj[j] + 9]);
            const float4 xv = x4[idx];
            float4 ov;
            const float s1 = (rrj[j] == 2) ? g1 : g0;
            const float s2 = (rrj[j] >= 1) ? g1 : g0;
            ov.x = xv.x * g0;
            ov.y = xv.y * s1;
            ov.z = xv.z * s2;
            ov.w = xv.w * g1;
            o4[idx] = ov;
        }
    }
}

extern "C" void kernel_launch(void* const* d_in, const int* in_sizes, int n_in,
                              void* d_out, int out_size, void* d_ws, size_t ws_size,
                              hipStream_t stream) {
    const float* x   = (const float*)d_in[0];
    const float* wh1 = (const float*)d_in[1];
    const float* wv1 = (const float*)d_in[2];
    const float* wh2 = (const float*)d_in[3];
    const float* wv2 = (const float*)d_in[4];
    const float* g   = (const float*)d_in[5];
    const float* b   = (const float*)d_in[6];
    const float* m   = (const float*)d_in[7];
    const float* v   = (const float*)d_in[8];

    mra_fused<<<dim3(2 * 8 * 256), dim3(128), 0, stream>>>(
        x, wh1, wv1, wh2, wv2, g, b, m, v, (float*)d_out);
}

// Round 10
// 174.143 us; speedup vs baseline: 1.1599x; 1.1599x over previous
//
#include <hip/hip_runtime.h>
#include <hip/hip_fp16.h>
#include <math.h>

#define BN_EPS 1e-5f

__device__ __forceinline__ float max3f(float a, float b, float c) {
    return fmaxf(fmaxf(a, b), c);
}

// One block per (b,c) plane. 256 threads = 4 waves. 8 blocks/CU (LDS 12.8 KB).
// Phase A: streaming separable blurpool(maxpool3x3(x)), stride-3 scalar loads in
//          consume layout + shfl for neighbors — NO LDS round-trip, no barriers.
// Phase B: four directional 33-tap convs (fp16 LDS reads, f32 accumulate)
// Phase C: out = x * gate[i/3][j/3]
__global__ __launch_bounds__(256, 8)
void mra_fused(const float* __restrict__ x,
               const float* __restrict__ wh1,
               const float* __restrict__ wv1,
               const float* __restrict__ wh2,
               const float* __restrict__ wv2,
               const float* __restrict__ bng,
               const float* __restrict__ bnb,
               const float* __restrict__ bnm,
               const float* __restrict__ bnv,
               float* __restrict__ out)
{
    __shared__ __align__(16) __half sxp_h[76][84];   // 12.77 KB, zero halo

    const int plane = blockIdx.x;       // b*256 + c
    const int c     = plane & 255;
    const int tid   = threadIdx.x;
    const int lane  = tid & 63;
    const int wv    = tid >> 6;
    const float* __restrict__ xp = x   + (size_t)plane * 36864;
    float* __restrict__       op = out + (size_t)plane * 36864;

    // ---- zero LDS plane (halo must be 0 for conv boundary) ----
    {
        int* z = (int*)&sxp_h[0][0];
        const int nInt = (76 * 84 * 2) / 4;   // 3192
        #pragma unroll
        for (int i = 0; i < 13; ++i) {
            const int idx = tid + (i << 8);
            if (idx < nInt) z[idx] = 0;
        }
    }
    __syncthreads();

    // ---- Phase A: streaming maxpool3x3(SAME) + blur4x4 stride-3 -> 64x64 ----
    // wave wv owns gate rows P0..P0+15 (P0=16*wv); lane owns output col q=lane.
    // lane loads cols 3q..3q+2 (consume layout); neighbors via shfl. 4-deep ring.
    {
        const int P0  = wv << 4;
        const int r0  = 3 * P0 - 2;
        const int col = 3 * lane;

        float c0r[4], c1r[4], c2r[4];
        auto issue = [&](int k, int s) {
            int r = r0 + k;
            r = r < 0 ? 0 : (r > 191 ? 191 : r);   // clamp == maxpool SAME
            const float* rp = xp + r * 192 + col;
            c0r[s] = rp[0]; c1r[s] = rp[1]; c2r[s] = rp[2];
        };
        issue(0, 0); issue(1, 1); issue(2, 2); issue(3, 3);

        float h[3][4];     // hmax history (centers 3q-1..3q+2) of last 3 rows
        float hb[3];       // blur-row values
        float hbp = 0.f;   // previous blur-row (center 3*P0-1)

        #pragma unroll
        for (int k = 0; k < 51; ++k) {
            const int s = k & 3;
            const float c0 = c0r[s], c1 = c1r[s], c2 = c2r[s];
            if (k + 4 < 51) issue(k + 4, s);

            float xm2 = __shfl_up(c1, 1);     // x[3q-2]
            float xm1 = __shfl_up(c2, 1);     // x[3q-1]
            float xp3 = __shfl_down(c0, 1);   // x[3q+3]
            if (lane == 0)  xm1 = c0;         // clamp col -1 -> 0
            if (lane == 63) xp3 = c2;         // clamp col 192 -> 191

            const float hm_m1 = max3f(xm2, xm1, c0);   // center 3q-1
            const float hm_0  = max3f(xm1, c0,  c1);   // center 3q
            const float hm_1  = max3f(c0,  c1,  c2);   // center 3q+1
            const float hm_2  = max3f(c1,  c2,  xp3);  // center 3q+2

            float* hk = h[k % 3];
            hk[0] = (lane == 0) ? hm_1 : hm_m1;  // reflect: center -1 == center 1
            hk[1] = hm_0; hk[2] = hm_1; hk[3] = hm_2;

            if (k >= 2) {
                const float* a = h[(k - 2) % 3];
                const float* b = h[(k - 1) % 3];
                const float* d = h[k % 3];
                const float e4 =
                      0.125f * max3f(a[0], b[0], d[0])
                    + 0.375f * max3f(a[1], b[1], d[1])
                    + 0.375f * max3f(a[2], b[2], d[2])
                    + 0.125f * max3f(a[3], b[3], d[3]);
                if (k == 2) {
                    hbp = e4;                       // center row 3*P0-1
                } else {
                    hb[k % 3] = e4;                 // k%3: 0->hb0, 1->hb1, 2->hb2
                    if (k % 3 == 2) {
                        const int i = (k - 5) / 3;  // gate row P0+i
                        float a_out;
                        if (i == 0 && wv == 0)      // top reflect: center -1 == 1
                            a_out = 0.375f * hb[0] + 0.5f * hb[1] + 0.125f * hb[2];
                        else
                            a_out = 0.125f * hbp + 0.375f * hb[0]
                                  + 0.375f * hb[1] + 0.125f * hb[2];
                        hbp = hb[2];
                        sxp_h[P0 + i + 6][lane + 8] = __float2half(a_out);
                    }
                }
            }
        }
    }
    __syncthreads();

    // ---- Phase B: four directional 33-tap depthwise convs ----
    // thread: gate row p = tid>>2 (0..63), strip q0..q0+15, q0 = 16*(tid&3)
    const int p  = tid >> 2;
    const int q0 = (tid & 3) << 4;
    float acc[16];
    #pragma unroll
    for (int i = 0; i < 16; ++i) acc[i] = 0.0f;

    const float* __restrict__ wh1p = wh1 + c * 33;
    const float* __restrict__ wv1p = wv1 + c * 33;
    const float* __restrict__ wh2p = wh2 + c * 33;
    const float* __restrict__ wv2p = wv2 + c * 33;

    #pragma unroll
    for (int e = -6; e <= 6; ++e) {
        // rbx[j] = X(p+e, q0-8+j); LDS row p+e+6 in [0,75], halo gives zeros
        float rbx[32];
        const __half* rowl = &sxp_h[p + e + 6][q0];
        #pragma unroll
        for (int u = 0; u < 8; ++u) {
            const __half2* h2p = (const __half2*)(rowl + 4 * u);
            const float2 f0 = __half22float2(h2p[0]);
            const float2 f1 = __half22float2(h2p[1]);
            rbx[4 * u + 0] = f0.x; rbx[4 * u + 1] = f0.y;
            rbx[4 * u + 2] = f1.x; rbx[4 * u + 3] = f1.y;
        }
        if (e >= -5 && e <= 5) {
            #pragma unroll
            for (int dw = -1; dw <= 1; ++dw) {
                const float wt = wh1p[(e + 5) * 3 + dw + 1];
                #pragma unroll
                for (int i = 0; i < 16; ++i) acc[i] += wt * rbx[i + dw + 8];
            }
            #pragma unroll
            for (int dw = -1; dw <= 1; ++dw) {
                const float wt = wh2p[(e + 5) * 3 + dw + 1];
                #pragma unroll
                for (int i = 0; i < 16; ++i) acc[i] += wt * rbx[i + dw - e + 8];
            }
        }
        if (e >= -1 && e <= 1) {
            #pragma unroll
            for (int dw = -5; dw <= 5; ++dw) {
                const float wt = wv1p[(e + 1) * 11 + dw + 5];
                #pragma unroll
                for (int i = 0; i < 16; ++i) acc[i] += wt * rbx[i + dw + 8];
            }
        }
        #pragma unroll
        for (int dh = -1; dh <= 1; ++dh) {
            const int dw = dh - e;
            if (dw >= -5 && dw <= 5) {
                const float wt = wv2p[(dh + 1) * 11 + dw + 5];
                #pragma unroll
                for (int i = 0; i < 16; ++i) acc[i] += wt * rbx[i + dh - e + 8];
            }
        }
    }

    // ---- BN (inference) + sigmoid -> gate, stored back over LDS plane (fp16) ----
    const float inv = bng[c] * rsqrtf(bnv[c] + BN_EPS);
    const float mu  = bnm[c];
    const float bt  = bnb[c];
    __syncthreads();   // all conv reads of sxp_h done before overwrite
    #pragma unroll
    for (int i = 0; i < 8; ++i) {
        const float a0 = (acc[2 * i]     - mu) * inv + bt;
        const float a1 = (acc[2 * i + 1] - mu) * inv + bt;
        const float g0 = 1.0f / (1.0f + __expf(-a0));
        const float g1 = 1.0f / (1.0f + __expf(-a1));
        *(__half2*)(&sxp_h[p + 6][q0 + 2 * i + 8]) = __floats2half2_rn(g0, g1);
    }
    __syncthreads();

    // ---- Phase C: out = x * gate[i/3][j/3], float4 streaming ----
    const float4* __restrict__ x4 = (const float4*)xp;
    float4* __restrict__       o4 = (float4*)op;
    int rowj[3], gcj[3], rrj[3];
    #pragma unroll
    for (int j = 0; j < 3; ++j) {
        const int idx0 = tid + (j << 8);
        const int rw   = idx0 / 48;            // 192/4=48 float4 per row
        const int c4   = idx0 - rw * 48;
        rowj[j] = rw;
        const int jb = c4 << 2;
        gcj[j] = jb / 3;
        rrj[j] = jb - 3 * gcj[j];
    }
    #pragma unroll
    for (int m = 0; m < 12; ++m) {
        #pragma unroll
        for (int j = 0; j < 3; ++j) {
            const int row = rowj[j] + (m << 4);
            const int idx = tid + ((m * 3 + j) << 8);
            const int gr  = row / 3 + 6;               // LDS gate row
            const float g0 = __half2float(sxp_h[gr][gcj[j] + 8]);
            const float g1 = __half2float(sxp_h[gr][gcj[j] + 9]);
            const float4 xv = x4[idx];
            float4 ov;
            const float s1 = (rrj[j] == 2) ? g1 : g0;
            const float s2 = (rrj[j] >= 1) ? g1 : g0;
            ov.x = xv.x * g0;
            ov.y = xv.y * s1;
            ov.z = xv.z * s2;
            ov.w = xv.w * g1;
            o4[idx] = ov;
        }
    }
}

extern "C" void kernel_launch(void* const* d_in, const int* in_sizes, int n_in,
                              void* d_out, int out_size, void* d_ws, size_t ws_size,
                              hipStream_t stream) {
    const float* x   = (const float*)d_in[0];
    const float* wh1 = (const float*)d_in[1];
    const float* wv1 = (const float*)d_in[2];
    const float* wh2 = (const float*)d_in[3];
    const float* wv2 = (const float*)d_in[4];
    const float* g   = (const float*)d_in[5];
    const float* b   = (const float*)d_in[6];
    const float* m   = (const float*)d_in[7];
    const float* v   = (const float*)d_in[8];

    mra_fused<<<dim3(8 * 256), dim3(256), 0, stream>>>(
        x, wh1, wv1, wh2, wv2, g, b, m, v, (float*)d_out);
}

// Round 11
// 167.597 us; speedup vs baseline: 1.2052x; 1.0391x over previous
//
#include <hip/hip_runtime.h>
#include <hip/hip_fp16.h>
#include <math.h>

#define BN_EPS 1e-5f

__device__ __forceinline__ float max3f(float a, float b, float c) {
    return fmaxf(fmaxf(a, b), c);
}

// One block per (b,c) plane. 512 threads = 8 waves. 4 blocks/CU resident (32-wave
// cap) out of 2048 -> two generations, continuous churn => cross-generation phase
// overlap (incoming blocks' A-reads hide under survivors' B/C).
// Phase A: streaming separable blurpool(maxpool3x3(x)), stride-3 scalar loads in
//          consume layout + shfl for neighbors — no LDS round-trip, no barriers.
// Phase B: four directional 33-tap convs (fp16 LDS reads, f32 accumulate)
// Phase C: out = x * gate[i/3][j/3]
__global__ __launch_bounds__(512, 8)
void mra_fused(const float* __restrict__ x,
               const float* __restrict__ wh1,
               const float* __restrict__ wv1,
               const float* __restrict__ wh2,
               const float* __restrict__ wv2,
               const float* __restrict__ bng,
               const float* __restrict__ bnb,
               const float* __restrict__ bnm,
               const float* __restrict__ bnv,
               float* __restrict__ out)
{
    __shared__ __align__(16) __half sxp_h[76][84];   // 12.77 KB, zero halo

    const int plane = blockIdx.x;       // b*256 + c
    const int c     = plane & 255;
    const int tid   = threadIdx.x;
    const int lane  = tid & 63;
    const int w     = tid >> 6;         // 0..7
    const float* __restrict__ xp = x   + (size_t)plane * 36864;
    float* __restrict__       op = out + (size_t)plane * 36864;

    // ---- zero LDS plane (halo must be 0 for conv boundary) ----
    {
        int* z = (int*)&sxp_h[0][0];
        const int nInt = (76 * 84 * 2) / 4;   // 3192
        #pragma unroll
        for (int i = 0; i < 7; ++i) {
            const int idx = tid + (i << 9);
            if (idx < nInt) z[idx] = 0;
        }
    }
    __syncthreads();

    // ---- Phase A: streaming maxpool3x3(SAME) + blur4x4 stride-3 -> 64x64 ----
    // wave w owns gate rows P0..P0+7 (P0=8w); lane owns output col q=lane.
    // lane loads cols 3q..3q+2 (consume layout); neighbors via shfl. 4-deep ring.
    {
        const int P0  = w << 3;
        const int r0  = 3 * P0 - 2;
        const int col = 3 * lane;

        float c0r[4], c1r[4], c2r[4];
        auto issue = [&](int k, int s) {
            int r = r0 + k;
            r = r < 0 ? 0 : (r > 191 ? 191 : r);   // clamp == maxpool SAME
            const float* rp = xp + r * 192 + col;
            c0r[s] = rp[0]; c1r[s] = rp[1]; c2r[s] = rp[2];
        };
        issue(0, 0); issue(1, 1); issue(2, 2); issue(3, 3);

        float h[3][4];     // hmax history (centers 3q-1..3q+2) of last 3 rows
        float hb[3];       // blur-row values
        float hbp = 0.f;   // previous blur-row (center 3*P0-1)

        #pragma unroll
        for (int k = 0; k < 27; ++k) {
            const int s = k & 3;
            const float c0 = c0r[s], c1 = c1r[s], c2 = c2r[s];
            if (k + 4 < 27) issue(k + 4, s);

            float xm2 = __shfl_up(c1, 1);     // x[3q-2]
            float xm1 = __shfl_up(c2, 1);     // x[3q-1]
            float xp3 = __shfl_down(c0, 1);   // x[3q+3]
            if (lane == 0)  xm1 = c0;         // clamp col -1 -> 0
            if (lane == 63) xp3 = c2;         // clamp col 192 -> 191

            const float hm_m1 = max3f(xm2, xm1, c0);   // center 3q-1
            const float hm_0  = max3f(xm1, c0,  c1);   // center 3q
            const float hm_1  = max3f(c0,  c1,  c2);   // center 3q+1
            const float hm_2  = max3f(c1,  c2,  xp3);  // center 3q+2

            float* hk = h[k % 3];
            hk[0] = (lane == 0) ? hm_1 : hm_m1;  // reflect: center -1 == center 1
            hk[1] = hm_0; hk[2] = hm_1; hk[3] = hm_2;

            if (k >= 2) {
                const float* a = h[(k - 2) % 3];
                const float* b = h[(k - 1) % 3];
                const float* d = h[k % 3];
                const float e4 =
                      0.125f * max3f(a[0], b[0], d[0])
                    + 0.375f * max3f(a[1], b[1], d[1])
                    + 0.375f * max3f(a[2], b[2], d[2])
                    + 0.125f * max3f(a[3], b[3], d[3]);
                if (k == 2) {
                    hbp = e4;                       // center row 3*P0-1
                } else {
                    hb[k % 3] = e4;                 // k%3: 0->hb0, 1->hb1, 2->hb2
                    if (k % 3 == 2) {
                        const int i = (k - 5) / 3;  // gate row P0+i
                        float a_out;
                        if (i == 0 && w == 0)       // top reflect: center -1 == 1
                            a_out = 0.375f * hb[0] + 0.5f * hb[1] + 0.125f * hb[2];
                        else
                            a_out = 0.125f * hbp + 0.375f * hb[0]
                                  + 0.375f * hb[1] + 0.125f * hb[2];
                        hbp = hb[2];
                        sxp_h[P0 + i + 6][lane + 8] = __float2half(a_out);
                    }
                }
            }
        }
    }
    __syncthreads();

    // ---- Phase B: four directional 33-tap depthwise convs ----
    // thread: gate row p = tid>>3 (0..63), strip q0..q0+7, q0 = 8*(tid&7)
    const int p  = tid >> 3;
    const int q0 = (tid & 7) << 3;
    float acc[8];
    #pragma unroll
    for (int i = 0; i < 8; ++i) acc[i] = 0.0f;

    const float* __restrict__ wh1p = wh1 + c * 33;
    const float* __restrict__ wv1p = wv1 + c * 33;
    const float* __restrict__ wh2p = wh2 + c * 33;
    const float* __restrict__ wv2p = wv2 + c * 33;

    #pragma unroll
    for (int e = -6; e <= 6; ++e) {
        // rbx[j] = X(p+e, q0-8+j), j=0..23 (LDS col q0+j, halo gives zeros);
        // used j in [2,22]
        float rbx[24];
        const __half* rowl = &sxp_h[p + e + 6][q0];
        #pragma unroll
        for (int u = 0; u < 6; ++u) {
            const __half2* h2p = (const __half2*)(rowl + 4 * u);
            const float2 f0 = __half22float2(h2p[0]);
            const float2 f1 = __half22float2(h2p[1]);
            rbx[4 * u + 0] = f0.x; rbx[4 * u + 1] = f0.y;
            rbx[4 * u + 2] = f1.x; rbx[4 * u + 3] = f1.y;
        }
        if (e >= -5 && e <= 5) {
            #pragma unroll
            for (int dw = -1; dw <= 1; ++dw) {
                const float wt = wh1p[(e + 5) * 3 + dw + 1];
                #pragma unroll
                for (int i = 0; i < 8; ++i) acc[i] += wt * rbx[i + dw + 8];
            }
            #pragma unroll
            for (int dw = -1; dw <= 1; ++dw) {
                const float wt = wh2p[(e + 5) * 3 + dw + 1];
                #pragma unroll
                for (int i = 0; i < 8; ++i) acc[i] += wt * rbx[i + dw - e + 8];
            }
        }
        if (e >= -1 && e <= 1) {
            #pragma unroll
            for (int dw = -5; dw <= 5; ++dw) {
                const float wt = wv1p[(e + 1) * 11 + dw + 5];
                #pragma unroll
                for (int i = 0; i < 8; ++i) acc[i] += wt * rbx[i + dw + 8];
            }
        }
        #pragma unroll
        for (int dh = -1; dh <= 1; ++dh) {
            const int dw = dh - e;
            if (dw >= -5 && dw <= 5) {
                const float wt = wv2p[(dh + 1) * 11 + dw + 5];
                #pragma unroll
                for (int i = 0; i < 8; ++i) acc[i] += wt * rbx[i + dh - e + 8];
            }
        }
    }

    // ---- BN (inference) + sigmoid -> gate, stored back over LDS plane (fp16) ----
    const float inv = bng[c] * rsqrtf(bnv[c] + BN_EPS);
    const float mu  = bnm[c];
    const float bt  = bnb[c];
    __syncthreads();   // all conv reads of sxp_h done before overwrite
    #pragma unroll
    for (int i = 0; i < 4; ++i) {
        const float a0 = (acc[2 * i]     - mu) * inv + bt;
        const float a1 = (acc[2 * i + 1] - mu) * inv + bt;
        const float g0 = 1.0f / (1.0f + __expf(-a0));
        const float g1 = 1.0f / (1.0f + __expf(-a1));
        *(__half2*)(&sxp_h[p + 6][q0 + 2 * i + 8]) = __floats2half2_rn(g0, g1);
    }
    __syncthreads();

    // ---- Phase C: out = x * gate[i/3][j/3], float4 streaming ----
    const float4* __restrict__ x4 = (const float4*)xp;
    float4* __restrict__       o4 = (float4*)op;
    int rowj[3], gcj[3], rrj[3];
    #pragma unroll
    for (int j = 0; j < 3; ++j) {
        const int idx0 = tid + (j << 9);
        const int rw   = idx0 / 48;            // 192/4=48 float4 per row
        const int c4   = idx0 - rw * 48;
        rowj[j] = rw;                          // 0..31
        const int jb = c4 << 2;
        gcj[j] = jb / 3;
        rrj[j] = jb - 3 * gcj[j];
    }
    #pragma unroll
    for (int m = 0; m < 6; ++m) {
        #pragma unroll
        for (int j = 0; j < 3; ++j) {
            const int row = rowj[j] + (m << 5);
            const int idx = tid + ((m * 3 + j) << 9);
            const int gr  = row / 3 + 6;               // LDS gate row
            const float g0 = __half2float(sxp_h[gr][gcj[j] + 8]);
            const float g1 = __half2float(sxp_h[gr][gcj[j] + 9]);
            const float4 xv = x4[idx];
            float4 ov;
            const float s1 = (rrj[j] == 2) ? g1 : g0;
            const float s2 = (rrj[j] >= 1) ? g1 : g0;
            ov.x = xv.x * g0;
            ov.y = xv.y * s1;
            ov.z = xv.z * s2;
            ov.w = xv.w * g1;
            o4[idx] = ov;
        }
    }
}

extern "C" void kernel_launch(void* const* d_in, const int* in_sizes, int n_in,
                              void* d_out, int out_size, void* d_ws, size_t ws_size,
                              hipStream_t stream) {
    const float* x   = (const float*)d_in[0];
    const float* wh1 = (const float*)d_in[1];
    const float* wv1 = (const float*)d_in[2];
    const float* wh2 = (const float*)d_in[3];
    const float* wv2 = (const float*)d_in[4];
    const float* g   = (const float*)d_in[5];
    const float* b   = (const float*)d_in[6];
    const float* m   = (const float*)d_in[7];
    const float* v   = (const float*)d_in[8];

    mra_fused<<<dim3(8 * 256), dim3(512), 0, stream>>>(
        x, wh1, wv1, wh2, wv2, g, b, m, v, (float*)d_out);
}

// Round 12
// 164.772 us; speedup vs baseline: 1.2258x; 1.0171x over previous
//
#include <hip/hip_runtime.h>
#include <hip/hip_fp16.h>
#include <math.h>

#define BN_EPS 1e-5f

__device__ __forceinline__ float max3f(float a, float b, float c) {
    return fmaxf(fmaxf(a, b), c);
}

// One block per (b,c) plane. 512 threads = 8 waves. 4 blocks/CU resident.
// Wave-local pipeline: after the single A->B barrier, each wave flows
// B -> BN -> C with NO block-wide sync (gate goes to a separate LDS buffer;
// wave w's C rows 24w..24w+23 need only gate rows 8w..8w+7 = wave w's own
// B outputs). Waves drain into C (HBM writes) while others still run B (VALU).
// Phase A: streaming separable blurpool(maxpool3x3(x)), stride-3 loads in
//          consume layout + shfl for neighbors — no LDS round-trip.
// Phase B: four directional 33-tap convs (fp16 LDS reads, f32 accumulate)
// Phase C: out = x * gate[i/3][j/3]
__global__ __launch_bounds__(512, 8)
void mra_fused(const float* __restrict__ x,
               const float* __restrict__ wh1,
               const float* __restrict__ wv1,
               const float* __restrict__ wh2,
               const float* __restrict__ wv2,
               const float* __restrict__ bng,
               const float* __restrict__ bnb,
               const float* __restrict__ bnm,
               const float* __restrict__ bnv,
               float* __restrict__ out)
{
    __shared__ __align__(16) __half sxp_h[76][84];   // x_tem, 12.77 KB, zero halo
    __shared__ __align__(16) __half gate_h[64][72];  // gate, 9 KB

    const int plane = blockIdx.x;       // b*256 + c
    const int c     = plane & 255;
    const int tid   = threadIdx.x;
    const int lane  = tid & 63;
    const int w     = tid >> 6;         // 0..7
    const float* __restrict__ xp = x   + (size_t)plane * 36864;
    float* __restrict__       op = out + (size_t)plane * 36864;

    // ---- zero x_tem plane (halo must be 0 for conv boundary) ----
    {
        int* z = (int*)&sxp_h[0][0];
        const int nInt = (76 * 84 * 2) / 4;   // 3192
        #pragma unroll
        for (int i = 0; i < 7; ++i) {
            const int idx = tid + (i << 9);
            if (idx < nInt) z[idx] = 0;
        }
    }
    __syncthreads();

    // ---- Phase A: streaming maxpool3x3(SAME) + blur4x4 stride-3 -> 64x64 ----
    // wave w owns gate rows P0..P0+7 (P0=8w); lane owns output col q=lane.
    {
        const int P0  = w << 3;
        const int r0  = 3 * P0 - 2;
        const int col = 3 * lane;

        float c0r[4], c1r[4], c2r[4];
        auto issue = [&](int k, int s) {
            int r = r0 + k;
            r = r < 0 ? 0 : (r > 191 ? 191 : r);   // clamp == maxpool SAME
            const float* rp = xp + r * 192 + col;
            c0r[s] = rp[0]; c1r[s] = rp[1]; c2r[s] = rp[2];
        };
        issue(0, 0); issue(1, 1); issue(2, 2); issue(3, 3);

        float h[3][4];     // hmax history (centers 3q-1..3q+2) of last 3 rows
        float hb[3];       // blur-row values
        float hbp = 0.f;   // previous blur-row (center 3*P0-1)

        #pragma unroll
        for (int k = 0; k < 27; ++k) {
            const int s = k & 3;
            const float c0 = c0r[s], c1 = c1r[s], c2 = c2r[s];
            if (k + 4 < 27) issue(k + 4, s);

            float xm2 = __shfl_up(c1, 1);     // x[3q-2]
            float xm1 = __shfl_up(c2, 1);     // x[3q-1]
            float xp3 = __shfl_down(c0, 1);   // x[3q+3]
            if (lane == 0)  xm1 = c0;         // clamp col -1 -> 0
            if (lane == 63) xp3 = c2;         // clamp col 192 -> 191

            const float hm_m1 = max3f(xm2, xm1, c0);   // center 3q-1
            const float hm_0  = max3f(xm1, c0,  c1);   // center 3q
            const float hm_1  = max3f(c0,  c1,  c2);   // center 3q+1
            const float hm_2  = max3f(c1,  c2,  xp3);  // center 3q+2

            float* hk = h[k % 3];
            hk[0] = (lane == 0) ? hm_1 : hm_m1;  // reflect: center -1 == center 1
            hk[1] = hm_0; hk[2] = hm_1; hk[3] = hm_2;

            if (k >= 2) {
                const float* a = h[(k - 2) % 3];
                const float* b = h[(k - 1) % 3];
                const float* d = h[k % 3];
                const float e4 =
                      0.125f * max3f(a[0], b[0], d[0])
                    + 0.375f * max3f(a[1], b[1], d[1])
                    + 0.375f * max3f(a[2], b[2], d[2])
                    + 0.125f * max3f(a[3], b[3], d[3]);
                if (k == 2) {
                    hbp = e4;                       // center row 3*P0-1
                } else {
                    hb[k % 3] = e4;                 // k%3: 0->hb0, 1->hb1, 2->hb2
                    if (k % 3 == 2) {
                        const int i = (k - 5) / 3;  // gate row P0+i
                        float a_out;
                        if (i == 0 && w == 0)       // top reflect: center -1 == 1
                            a_out = 0.375f * hb[0] + 0.5f * hb[1] + 0.125f * hb[2];
                        else
                            a_out = 0.125f * hbp + 0.375f * hb[0]
                                  + 0.375f * hb[1] + 0.125f * hb[2];
                        hbp = hb[2];
                        sxp_h[P0 + i + 6][lane + 8] = __float2half(a_out);
                    }
                }
            }
        }
    }
    __syncthreads();   // A -> B: B reads neighbor waves' x_tem rows (+-6)

    // ---- Phase B: four directional 33-tap depthwise convs ----
    // thread: gate row p = tid>>3 (0..63, wave-local 8 rows), strip q0 = 8*(tid&7)
    const int p  = tid >> 3;
    const int q0 = (tid & 7) << 3;
    float acc[8];
    #pragma unroll
    for (int i = 0; i < 8; ++i) acc[i] = 0.0f;

    const float* __restrict__ wh1p = wh1 + c * 33;
    const float* __restrict__ wv1p = wv1 + c * 33;
    const float* __restrict__ wh2p = wh2 + c * 33;
    const float* __restrict__ wv2p = wv2 + c * 33;

    #pragma unroll
    for (int e = -6; e <= 6; ++e) {
        // rbx[j] = X(p+e, q0-8+j), j=0..23 (LDS col q0+j, halo gives zeros)
        float rbx[24];
        const __half* rowl = &sxp_h[p + e + 6][q0];
        #pragma unroll
        for (int u = 0; u < 6; ++u) {
            const __half2* h2p = (const __half2*)(rowl + 4 * u);
            const float2 f0 = __half22float2(h2p[0]);
            const float2 f1 = __half22float2(h2p[1]);
            rbx[4 * u + 0] = f0.x; rbx[4 * u + 1] = f0.y;
            rbx[4 * u + 2] = f1.x; rbx[4 * u + 3] = f1.y;
        }
        if (e >= -5 && e <= 5) {
            #pragma unroll
            for (int dw = -1; dw <= 1; ++dw) {
                const float wt = wh1p[(e + 5) * 3 + dw + 1];
                #pragma unroll
                for (int i = 0; i < 8; ++i) acc[i] += wt * rbx[i + dw + 8];
            }
            #pragma unroll
            for (int dw = -1; dw <= 1; ++dw) {
                const float wt = wh2p[(e + 5) * 3 + dw + 1];
                #pragma unroll
                for (int i = 0; i < 8; ++i) acc[i] += wt * rbx[i + dw - e + 8];
            }
        }
        if (e >= -1 && e <= 1) {
            #pragma unroll
            for (int dw = -5; dw <= 5; ++dw) {
                const float wt = wv1p[(e + 1) * 11 + dw + 5];
                #pragma unroll
                for (int i = 0; i < 8; ++i) acc[i] += wt * rbx[i + dw + 8];
            }
        }
        #pragma unroll
        for (int dh = -1; dh <= 1; ++dh) {
            const int dw = dh - e;
            if (dw >= -5 && dw <= 5) {
                const float wt = wv2p[(dh + 1) * 11 + dw + 5];
                #pragma unroll
                for (int i = 0; i < 8; ++i) acc[i] += wt * rbx[i + dh - e + 8];
            }
        }
    }

    // ---- BN + sigmoid -> gate buffer (separate LDS; no overwrite hazard) ----
    const float inv = bng[c] * rsqrtf(bnv[c] + BN_EPS);
    const float mu  = bnm[c];
    const float bt  = bnb[c];
    #pragma unroll
    for (int i = 0; i < 4; ++i) {
        const float a0 = (acc[2 * i]     - mu) * inv + bt;
        const float a1 = (acc[2 * i + 1] - mu) * inv + bt;
        const float g0 = 1.0f / (1.0f + __expf(-a0));
        const float g1 = 1.0f / (1.0f + __expf(-a1));
        *(__half2*)(&gate_h[p][q0 + 2 * i]) = __floats2half2_rn(g0, g1);
    }
    __builtin_amdgcn_wave_barrier();   // order BN ds_writes before C ds_reads
                                       // (HW executes a wave's LDS ops in order)

    // ---- Phase C (wave-local): out rows 24w..24w+23 = x * gate ----
    const float4* __restrict__ x4 = (const float4*)xp + w * 1152;  // 24*48
    float4* __restrict__       o4 = (float4*)op       + w * 1152;
    int rlj[3], gcj[3], rrj[3];
    #pragma unroll
    for (int j = 0; j < 3; ++j) {
        const int idx0 = lane + (j << 6);
        const int rw   = idx0 / 48;            // 0..3
        const int c4   = idx0 - rw * 48;
        rlj[j] = rw;
        const int jb = c4 << 2;
        gcj[j] = jb / 3;
        rrj[j] = jb - 3 * gcj[j];
    }
    #pragma unroll
    for (int u = 0; u < 6; ++u) {
        #pragma unroll
        for (int j = 0; j < 3; ++j) {
            const int row_l = rlj[j] + (u << 2);       // 0..23
            const int idx   = lane + ((u * 3 + j) << 6);
            const int gr    = (w << 3) + row_l / 3;    // gate row 8w..8w+7
            const float g0 = __half2float(gate_h[gr][gcj[j]]);
            const float g1 = __half2float(gate_h[gr][gcj[j] + 1]);
            const float4 xv = x4[idx];
            float4 ov;
            const float s1 = (rrj[j] == 2) ? g1 : g0;
            const float s2 = (rrj[j] >= 1) ? g1 : g0;
            ov.x = xv.x * g0;
            ov.y = xv.y * s1;
            ov.z = xv.z * s2;
            ov.w = xv.w * g1;
            o4[idx] = ov;
        }
    }
}

extern "C" void kernel_launch(void* const* d_in, const int* in_sizes, int n_in,
                              void* d_out, int out_size, void* d_ws, size_t ws_size,
                              hipStream_t stream) {
    const float* x   = (const float*)d_in[0];
    const float* wh1 = (const float*)d_in[1];
    const float* wv1 = (const float*)d_in[2];
    const float* wh2 = (const float*)d_in[3];
    const float* wv2 = (const float*)d_in[4];
    const float* g   = (const float*)d_in[5];
    const float* b   = (const float*)d_in[6];
    const float* m   = (const float*)d_in[7];
    const float* v   = (const float*)d_in[8];

    mra_fused<<<dim3(8 * 256), dim3(512), 0, stream>>>(
        x, wh1, wv1, wh2, wv2, g, b, m, v, (float*)d_out);
}

// Round 15
// 156.550 us; speedup vs baseline: 1.2902x; 1.0525x over previous
//
#include <hip/hip_runtime.h>
#include <hip/hip_fp16.h>
#include <math.h>

#define BN_EPS 1e-5f

typedef _Float16 h2v __attribute__((ext_vector_type(2)));

__device__ __forceinline__ float max3f(float a, float b, float c) {
    return fmaxf(fmaxf(a, b), c);
}
__device__ __forceinline__ float fdot2u(uint32_t a, uint32_t b, float c) {
    union U { uint32_t u; h2v h; } ua, ub;
    ua.u = a; ub.u = b;
    return __builtin_amdgcn_fdot2(ua.h, ub.h, c, false);
}
__device__ __forceinline__ uint32_t pack2(float a, float b) {
    union U { uint32_t u; h2v h; } x;
    x.h.x = (_Float16)a; x.h.y = (_Float16)b; return x.u;
}

// One block per (b,c) plane. 512 threads = 8 waves. 4 blocks/CU resident.
// Phase A: streaming blurpool(maxpool3x3(x)), consume-layout loads + shfl.
// Phase B: four directional 33-tap convs via v_dot2_f32_f16 (fp16 pairs,
//          f32 accum); weights pre-packed to an LDS table once per block.
// Phase C: wave-local out = x * gate (no block sync after B).
__global__ __launch_bounds__(512, 8)
void mra_fused(const float* __restrict__ x,
               const float* __restrict__ wh1,
               const float* __restrict__ wv1,
               const float* __restrict__ wh2,
               const float* __restrict__ wv2,
               const float* __restrict__ bng,
               const float* __restrict__ bnb,
               const float* __restrict__ bnm,
               const float* __restrict__ bnv,
               float* __restrict__ out)
{
    __shared__ __align__(16) __half sxp_h[76][84];   // x_tem, 12.77 KB, zero halo
    __shared__ __align__(16) __half gate_h[64][72];  // gate, 9 KB
    __shared__ __align__(16) uint32_t wtab[13][12];  // packed fp16 weight pairs

    const int plane = blockIdx.x;       // b*256 + c
    const int c     = plane & 255;
    const int tid   = threadIdx.x;
    const int lane  = tid & 63;
    const int w     = tid >> 6;         // 0..7
    const float* __restrict__ xp = x   + (size_t)plane * 36864;
    float* __restrict__       op = out + (size_t)plane * 36864;

    const float* __restrict__ wh1p = wh1 + c * 33;
    const float* __restrict__ wv1p = wv1 + c * 33;
    const float* __restrict__ wh2p = wh2 + c * 33;
    const float* __restrict__ wv2p = wv2 + c * 33;

    // ---- zero x_tem plane (halo must be 0 for conv boundary) ----
    {
        int* z = (int*)&sxp_h[0][0];
        const int nInt = (76 * 84 * 2) / 4;   // 3192
        #pragma unroll
        for (int i = 0; i < 7; ++i) {
            const int idx = tid + (i << 9);
            if (idx < nInt) z[idx] = 0;
        }
    }
    // ---- pack fp16 weight-pair table (one thread per e-row) ----
    if (tid < 13) {
        const int e = tid - 6;
        uint32_t* wr = wtab[tid];
        #pragma unroll
        for (int s = 0; s < 12; ++s) wr[s] = 0;
        if (e >= -5 && e <= 5) {
            const float* a1 = wh1p + (e + 5) * 3;
            wr[0] = pack2(a1[0], a1[1]); wr[1] = pack2(a1[2], 0.f);
            const float* a2 = wh2p + (e + 5) * 3;
            wr[2] = pack2(a2[0], a2[1]); wr[3] = pack2(a2[2], 0.f);
        }
        if (e >= -4 && e <= 4) {
            wr[4] = pack2(wv2p[4 - e], wv2p[16 - e]);
            wr[5] = pack2(wv2p[28 - e], 0.f);
        } else if (e == 5)  wr[4] = pack2(wv2p[11], wv2p[23]);
        else if (e == -5)   wr[4] = pack2(wv2p[9],  wv2p[21]);
        else if (e == 6)    wr[4] = pack2(wv2p[22], 0.f);
        else                wr[4] = pack2(wv2p[10], 0.f);   // e == -6
        if (e >= -1 && e <= 1) {
            const float* a3 = wv1p + (e + 1) * 11;
            wr[6]  = pack2(a3[0], a3[1]); wr[7]  = pack2(a3[2], a3[3]);
            wr[8]  = pack2(a3[4], a3[5]); wr[9]  = pack2(a3[6], a3[7]);
            wr[10] = pack2(a3[8], a3[9]); wr[11] = pack2(a3[10], 0.f);
        }
    }
    __syncthreads();

    // ---- Phase A: streaming maxpool3x3(SAME) + blur4x4 stride-3 -> 64x64 ----
    {
        const int P0  = w << 3;
        const int r0  = 3 * P0 - 2;
        const int col = 3 * lane;

        float c0r[4], c1r[4], c2r[4];
        auto issue = [&](int k, int s) {
            int r = r0 + k;
            r = r < 0 ? 0 : (r > 191 ? 191 : r);   // clamp == maxpool SAME
            const float* rp = xp + r * 192 + col;
            c0r[s] = rp[0]; c1r[s] = rp[1]; c2r[s] = rp[2];
        };
        issue(0, 0); issue(1, 1); issue(2, 2); issue(3, 3);

        float h[3][4];
        float hb[3];
        float hbp = 0.f;

        #pragma unroll
        for (int k = 0; k < 27; ++k) {
            const int s = k & 3;
            const float c0 = c0r[s], c1 = c1r[s], c2 = c2r[s];
            if (k + 4 < 27) issue(k + 4, s);

            float xm2 = __shfl_up(c1, 1);
            float xm1 = __shfl_up(c2, 1);
            float xp3 = __shfl_down(c0, 1);
            if (lane == 0)  xm1 = c0;
            if (lane == 63) xp3 = c2;

            const float hm_m1 = max3f(xm2, xm1, c0);
            const float hm_0  = max3f(xm1, c0,  c1);
            const float hm_1  = max3f(c0,  c1,  c2);
            const float hm_2  = max3f(c1,  c2,  xp3);

            float* hk = h[k % 3];
            hk[0] = (lane == 0) ? hm_1 : hm_m1;  // reflect: center -1 == center 1
            hk[1] = hm_0; hk[2] = hm_1; hk[3] = hm_2;

            if (k >= 2) {
                const float* a = h[(k - 2) % 3];
                const float* b = h[(k - 1) % 3];
                const float* d = h[k % 3];
                const float e4 =
                      0.125f * max3f(a[0], b[0], d[0])
                    + 0.375f * max3f(a[1], b[1], d[1])
                    + 0.375f * max3f(a[2], b[2], d[2])
                    + 0.125f * max3f(a[3], b[3], d[3]);
                if (k == 2) {
                    hbp = e4;
                } else {
                    hb[k % 3] = e4;
                    if (k % 3 == 2) {
                        const int i = (k - 5) / 3;
                        float a_out;
                        if (i == 0 && w == 0)
                            a_out = 0.375f * hb[0] + 0.5f * hb[1] + 0.125f * hb[2];
                        else
                            a_out = 0.125f * hbp + 0.375f * hb[0]
                                  + 0.375f * hb[1] + 0.125f * hb[2];
                        hbp = hb[2];
                        sxp_h[(w << 3) + i + 6][lane + 8] = __float2half(a_out);
                    }
                }
            }
        }
    }
    __syncthreads();   // A -> B

    // ---- Phase B: four directional convs via fdot2 ----
    // thread: gate row p = tid>>3, cols q0..q0+7, q0 = 8*(tid&7)
    // data halves X(j) = sxp_h[p+e+6][q0+j], j=0..23
    // du[u]=(X(2u),X(2u+1)), su[u]=(X(2u+1),X(2u+2))
    const int p  = tid >> 3;
    const int q0 = (tid & 7) << 3;
    float acc[8];
    #pragma unroll
    for (int i = 0; i < 8; ++i) acc[i] = 0.0f;

    #pragma unroll
    for (int e = -6; e <= 6; ++e) {
        const uint2* drow = (const uint2*)&sxp_h[p + e + 6][q0];
        uint32_t du[12], su[11];
        #pragma unroll
        for (int u2 = 0; u2 < 6; ++u2) {
            const uint2 t = drow[u2];
            du[2 * u2] = t.x; du[2 * u2 + 1] = t.y;
        }
        #pragma unroll
        for (int u = 0; u < 11; ++u)
            su[u] = __builtin_amdgcn_alignbit(du[u + 1], du[u], 16);

        const uint2* wrow = (const uint2*)&wtab[e + 6][0];
        const uint2 wa = wrow[0], wb = wrow[1], wc = wrow[2];

        auto RUN3 = [&](float a, int j0, uint32_t pA, uint32_t pB) -> float {
            const int u = j0 >> 1;
            if (j0 & 1) { a = fdot2u(su[u], pA, a); a = fdot2u(su[u + 1], pB, a); }
            else        { a = fdot2u(du[u], pA, a); a = fdot2u(du[u + 1], pB, a); }
            return a;
        };
        auto RUN1 = [&](float a, int j0, uint32_t pA) -> float {
            const int u = j0 >> 1;
            return (j0 & 1) ? fdot2u(su[u], pA, a) : fdot2u(du[u], pA, a);
        };

        if (e >= -5 && e <= 5) {
            #pragma unroll
            for (int i = 0; i < 8; ++i) {
                acc[i] = RUN3(acc[i], i + 7, wa.x, wa.y);        // x_h1
                acc[i] = RUN3(acc[i], i + 7 - e, wb.x, wb.y);    // x_h2 (anti-diag)
            }
        }
        if (e >= -4 && e <= 4) {                                  // x_w2 (diag)
            #pragma unroll
            for (int i = 0; i < 8; ++i) acc[i] = RUN3(acc[i], i + 7 - e, wc.x, wc.y);
        } else if (e == 5) {
            #pragma unroll
            for (int i = 0; i < 8; ++i) acc[i] = RUN1(acc[i], i + 3, wc.x);
        } else if (e == -5) {
            // taps: dh=-1 -> j=i+12 (w=wv2p[9]), dh=0 -> j=i+13 (w=wv2p[21])
            // (was i+11 in round 13 -- off-by-one, absmax 0.60)
            #pragma unroll
            for (int i = 0; i < 8; ++i) acc[i] = RUN1(acc[i], i + 12, wc.x);
        } else if (e == 6) {
            #pragma unroll
            for (int i = 0; i < 8; ++i) acc[i] = RUN1(acc[i], i + 3, wc.x);
        } else {  // e == -6
            #pragma unroll
            for (int i = 0; i < 8; ++i) acc[i] = RUN1(acc[i], i + 13, wc.x);
        }
        if (e >= -1 && e <= 1) {                                  // x_w1
            const uint2 wd = wrow[3], we_ = wrow[4], wf_ = wrow[5];
            const uint32_t wp[6] = {wd.x, wd.y, we_.x, we_.y, wf_.x, wf_.y};
            #pragma unroll
            for (int i = 0; i < 8; ++i) {
                const int j0 = i + 3;
                const int u  = j0 >> 1;
                float a = acc[i];
                #pragma unroll
                for (int kk = 0; kk < 6; ++kk)
                    a = (j0 & 1) ? fdot2u(su[u + kk], wp[kk], a)
                                 : fdot2u(du[u + kk], wp[kk], a);
                acc[i] = a;
            }
        }
    }

    // ---- BN + sigmoid -> gate buffer (separate LDS; no overwrite hazard) ----
    const float inv = bng[c] * rsqrtf(bnv[c] + BN_EPS);
    const float mu  = bnm[c];
    const float bt  = bnb[c];
    #pragma unroll
    for (int i = 0; i < 4; ++i) {
        const float a0 = (acc[2 * i]     - mu) * inv + bt;
        const float a1 = (acc[2 * i + 1] - mu) * inv + bt;
        const float g0 = 1.0f / (1.0f + __expf(-a0));
        const float g1 = 1.0f / (1.0f + __expf(-a1));
        *(__half2*)(&gate_h[p][q0 + 2 * i]) = __floats2half2_rn(g0, g1);
    }
    __builtin_amdgcn_wave_barrier();   // order BN ds_writes before C ds_reads

    // ---- Phase C (wave-local): out rows 24w..24w+23 = x * gate ----
    const float4* __restrict__ x4 = (const float4*)xp + w * 1152;  // 24*48
    float4* __restrict__       o4 = (float4*)op       + w * 1152;
    int rlj[3], gcj[3], rrj[3];
    #pragma unroll
    for (int j = 0; j < 3; ++j) {
        const int idx0 = lane + (j << 6);
        const int rw   = idx0 / 48;            // 0..3
        const int c4   = idx0 - rw * 48;
        rlj[j] = rw;
        const int jb = c4 << 2;
        gcj[j] = jb / 3;
        rrj[j] = jb - 3 * gcj[j];
    }
    #pragma unroll
    for (int u = 0; u < 6; ++u) {
        #pragma unroll
        for (int j = 0; j < 3; ++j) {
            const int row_l = rlj[j] + (u << 2);       // 0..23
            const int idx   = lane + ((u * 3 + j) << 6);
            const int gr    = (w << 3) + row_l / 3;    // gate row 8w..8w+7
            const float g0 = __half2float(gate_h[gr][gcj[j]]);
            const float g1 = __half2float(gate_h[gr][gcj[j] + 1]);
            const float4 xv = x4[idx];
            float4 ov;
            const float s1 = (rrj[j] == 2) ? g1 : g0;
            const float s2 = (rrj[j] >= 1) ? g1 : g0;
            ov.x = xv.x * g0;
            ov.y = xv.y * s1;
            ov.z = xv.z * s2;
            ov.w = xv.w * g1;
            o4[idx] = ov;
        }
    }
}

extern "C" void kernel_launch(void* const* d_in, const int* in_sizes, int n_in,
                              void* d_out, int out_size, void* d_ws, size_t ws_size,
                              hipStream_t stream) {
    const float* x   = (const float*)d_in[0];
    const float* wh1 = (const float*)d_in[1];
    const float* wv1 = (const float*)d_in[2];
    const float* wh2 = (const float*)d_in[3];
    const float* wv2 = (const float*)d_in[4];
    const float* g   = (const float*)d_in[5];
    const float* b   = (const float*)d_in[6];
    const float* m   = (const float*)d_in[7];
    const float* v   = (const float*)d_in[8];

    mra_fused<<<dim3(8 * 256), dim3(512), 0, stream>>>(
        x, wh1, wv1, wh2, wv2, g, b, m, v, (float*)d_out);
}